// Round 8
// baseline (912.063 us; speedup 1.0000x reference)
//
#include <hip/hip_runtime.h>
#include <hip/hip_bf16.h>
#include <math.h>

// ---------------------------------------------------------------------------
// RobustDecoder: conv stem -> 4x selective-SSM (Mamba) layers -> pool -> heads
// Round 8: resubmit of round 7 (pod died before any bench ran — infra).
// scan v4 (B/C transposed to global L2-resident arrays, 2-deep pipelined
// loads, exp2), 2-stage GroupNorm stats, split xp-GEMM epilogue.
// ---------------------------------------------------------------------------

#define D_MODEL 256
#define D_INNER 512
#define N_LAYERS 4
#define N_DEPTHS 4
#define N_EMB 8192
#define BATCH 8

typedef __attribute__((ext_vector_type(8))) short short8;
typedef __attribute__((ext_vector_type(4))) float f32x4;

__device__ __forceinline__ unsigned short f2bf(float x) {
    unsigned u = __float_as_uint(x);
    u = (u + 0x7fffu + ((u >> 16) & 1u)) >> 16;
    return (unsigned short)u;
}

template <int CTRL>
__device__ __forceinline__ float dpp_add(float v) {
    int t = __builtin_amdgcn_update_dpp(0, __float_as_int(v), CTRL, 0xf, 0xf, true);
    return v + __int_as_float(t);
}

// ---------------------------------------------------------------------------
// conv1 v2: (8,3,128,128) -> (8,128,64,64), 3x3 stride2 pad1, + bias
// ---------------------------------------------------------------------------
__global__ __launch_bounds__(256) void conv1_k(const float* __restrict__ x,
                                               const float* __restrict__ w,
                                               const float* __restrict__ b,
                                               float* __restrict__ out) {
    __shared__ float xs[3][17][18];
    __shared__ float wsm[128][28];
    const int tid = threadIdx.x;
    const int bb = blockIdx.x >> 6;
    const int tile = blockIdx.x & 63;
    const int oh0 = (tile >> 3) * 8, ow0 = (tile & 7) * 8;

    for (int i = tid; i < 3456; i += 256) wsm[i / 27][i % 27] = w[i];
    for (int i = tid; i < 128; i += 256) wsm[i][27] = 0.f;

    const int ih0 = oh0 * 2 - 1, iw0 = ow0 * 2 - 1;
    for (int i = tid; i < 3 * 289; i += 256) {
        int ic = i / 289, rr = (i % 289) / 17, cc = i % 17;
        int ih = ih0 + rr, iw = iw0 + cc;
        float v = 0.f;
        if ((unsigned)ih < 128u && (unsigned)iw < 128u)
            v = x[((size_t)(bb * 3 + ic) * 128 + ih) * 128 + iw];
        xs[ic][rr][cc] = v;
    }
    __syncthreads();

    const int px = tid & 63, ph = px >> 3, pw = px & 7;
    const int oc0 = (tid >> 6) * 32;
    float xk[28];
#pragma unroll
    for (int ic = 0; ic < 3; ++ic)
#pragma unroll
        for (int r = 0; r < 3; ++r)
#pragma unroll
            for (int c = 0; c < 3; ++c)
                xk[ic * 9 + r * 3 + c] = xs[ic][ph * 2 + r][pw * 2 + c];
    xk[27] = 0.f;

    size_t obase = ((size_t)(bb * 128 + oc0) * 64 + oh0 + ph) * 64 + ow0 + pw;
#pragma unroll
    for (int oc = 0; oc < 32; ++oc) {
        float a = b[oc0 + oc];
#pragma unroll
        for (int k4 = 0; k4 < 7; ++k4) {
            float4 w4 = *(const float4*)&wsm[oc0 + oc][k4 * 4];
            a = fmaf(xk[k4 * 4 + 0], w4.x, a);
            a = fmaf(xk[k4 * 4 + 1], w4.y, a);
            a = fmaf(xk[k4 * 4 + 2], w4.z, a);
            a = fmaf(xk[k4 * 4 + 3], w4.w, a);
        }
        out[obase + (size_t)oc * 4096] = a;
    }
}

// ---------------------------------------------------------------------------
// GroupNorm stats, 2-stage. Stage1: 512 blocks, float4 partial sums.
// gn1 (NCHW contiguous group region): block bx covers floats [bx*8192, +8192)
// ---------------------------------------------------------------------------
__global__ __launch_bounds__(256) void gn_part_k(const float* __restrict__ x,
                                                 float* __restrict__ part) {
    const float4* p4 = (const float4*)(x + (size_t)blockIdx.x * 8192) + threadIdx.x;
    float s = 0.f, ss = 0.f;
#pragma unroll
    for (int i = 0; i < 8; ++i) {
        float4 v = p4[i * 256];
        s += v.x + v.y + v.z + v.w;
        ss += v.x * v.x + v.y * v.y + v.z * v.z + v.w * v.w;
    }
#pragma unroll
    for (int o = 32; o > 0; o >>= 1) {
        s += __shfl_down(s, o);
        ss += __shfl_down(ss, o);
    }
    __shared__ float sh[4], sh2[4];
    int lane = threadIdx.x & 63, wid = threadIdx.x >> 6;
    if (lane == 0) { sh[wid] = s; sh2[wid] = ss; }
    __syncthreads();
    if (threadIdx.x == 0) {
        part[blockIdx.x * 2] = sh[0] + sh[1] + sh[2] + sh[3];
        part[blockIdx.x * 2 + 1] = sh2[0] + sh2[1] + sh2[2] + sh2[3];
    }
}

// gn2 stage1 on NHWC f (8,1024,256), groups of 32 ch: block=(bg 0..63, sub 0..7)
__global__ __launch_bounds__(256) void gn2_part_k(const float* __restrict__ f,
                                                  float* __restrict__ part) {
    int bg = blockIdx.x >> 3, sub = blockIdx.x & 7;
    int b = bg >> 3, g = bg & 7;
    const float* base = f + (size_t)b * 262144 + g * 32;
    int col = (threadIdx.x & 7) * 4;
    int r0 = sub * 128 + (threadIdx.x >> 3);
    float s = 0.f, ss = 0.f;
#pragma unroll
    for (int p = 0; p < 4; ++p) {
        float4 v = *(const float4*)(base + (size_t)(r0 + p * 32) * 256 + col);
        s += v.x + v.y + v.z + v.w;
        ss += v.x * v.x + v.y * v.y + v.z * v.z + v.w * v.w;
    }
#pragma unroll
    for (int o = 32; o > 0; o >>= 1) {
        s += __shfl_down(s, o);
        ss += __shfl_down(ss, o);
    }
    __shared__ float sh[4], sh2[4];
    int lane = threadIdx.x & 63, wid = threadIdx.x >> 6;
    if (lane == 0) { sh[wid] = s; sh2[wid] = ss; }
    __syncthreads();
    if (threadIdx.x == 0) {
        part[blockIdx.x * 2] = sh[0] + sh[1] + sh[2] + sh[3];
        part[blockIdx.x * 2 + 1] = sh2[0] + sh2[1] + sh2[2] + sh2[3];
    }
}

// Stage2: 64 threads, one per (batch,group): combine 8 partials -> stats
__global__ __launch_bounds__(64) void gn_reduce_k(const float* __restrict__ part,
                                                  float* __restrict__ stats, float invn) {
    int t = threadIdx.x;
    float S = 0.f, SS = 0.f;
#pragma unroll
    for (int i = 0; i < 8; ++i) {
        S += part[(t * 8 + i) * 2];
        SS += part[(t * 8 + i) * 2 + 1];
    }
    float mean = S * invn;
    float var = SS * invn - mean * mean;
    stats[t * 2] = mean;
    stats[t * 2 + 1] = rsqrtf(var + 1e-5f);
}

// GroupNorm apply + SiLU in place (NCHW)
__global__ __launch_bounds__(256) void gn_apply_k(float* __restrict__ x,
                                                  const float* __restrict__ stats,
                                                  const float* __restrict__ g,
                                                  const float* __restrict__ b,
                                                  int C, int cpg, int HW, int total) {
    int idx = blockIdx.x * 256 + threadIdx.x;
    if (idx >= total) return;
    int ch = (idx / HW) % C;
    int bb = idx / (HW * C);
    int bg = bb * (C / cpg) + ch / cpg;
    float mean = stats[bg * 2], rstd = stats[bg * 2 + 1];
    float v = (x[idx] - mean) * rstd * g[ch] + b[ch];
    x[idx] = v / (1.f + __expf(-v));
}

// ---------------------------------------------------------------------------
// NCHW fp32 -> NHWC bf16 tiled transpose: h1 (8,128,64,64) -> (8,4096,128)
// ---------------------------------------------------------------------------
__global__ __launch_bounds__(256) void nhwc_k(const float* __restrict__ src,
                                              unsigned short* __restrict__ dst) {
    __shared__ float tl[128][65];
    int b = blockIdx.x >> 6;
    int hw0 = (blockIdx.x & 63) * 64;
    int t = threadIdx.x;
#pragma unroll
    for (int p = 0; p < 32; ++p) {
        int c = p * 4 + (t >> 6);
        int hwi = t & 63;
        tl[c][hwi] = src[((size_t)(b * 128 + c)) * 4096 + hw0 + hwi];
    }
    __syncthreads();
#pragma unroll
    for (int p = 0; p < 16; ++p) {
        int hwi = p * 4 + (t >> 6);
        int c0 = (t & 63) * 2;
        unsigned short u0 = f2bf(tl[c0][hwi]);
        unsigned short u1 = f2bf(tl[c0 + 1][hwi]);
        unsigned int pk = (unsigned int)u0 | ((unsigned int)u1 << 16);
        *(unsigned int*)&dst[((size_t)(b * 4096 + hw0 + hwi)) * 128 + c0] = pk;
    }
}

// ---------------------------------------------------------------------------
// im2col (bf16): rows (b,oh,ow) 8192, cols K = (r*3+c)*128 + ic  (1152)
// ---------------------------------------------------------------------------
__global__ __launch_bounds__(256) void im2col_k(const unsigned short* __restrict__ nhwc,
                                                unsigned short* __restrict__ imcol) {
    int idx = blockIdx.x * 256 + threadIdx.x;  // 8192*9*8
    if (idx >= 8192 * 9 * 8) return;
    int chunk = idx & 7;
    int r3c = (idx >> 3) % 9;
    int row = idx / 72;
    int b = row >> 10, l = row & 1023;
    int oh = l >> 5, ow = l & 31;
    int r = r3c / 3, c = r3c % 3;
    int ih = 2 * oh - 1 + r, iw = 2 * ow - 1 + c;
    int4 v0 = make_int4(0, 0, 0, 0), v1 = make_int4(0, 0, 0, 0);
    if ((unsigned)ih < 64u && (unsigned)iw < 64u) {
        const int4* s = (const int4*)&nhwc[((size_t)(b * 4096 + ih * 64 + iw)) * 128 + chunk * 16];
        v0 = s[0];
        v1 = s[1];
    }
    int4* d = (int4*)&imcol[(size_t)row * 1152 + r3c * 128 + chunk * 16];
    d[0] = v0;
    d[1] = v1;
}

// ---------------------------------------------------------------------------
// MFMA bf16 GEMM: C[M,N] = A[M,K]_bf16 @ W[N,K]_bf16^T (+bias) (+=)
// 128x128 tile, 4 waves (2x2), BK=32, global_load_lds w16, b128 frag reads.
// MODE 0: normal epilogue into C (ldc). MODE 1 (xp-split): col<16 -> dtin
// (C, lda 16), 16..31 -> BTp[s][row], 32..47 -> CTp[s][row].
// ---------------------------------------------------------------------------
template <int BIAS, int ACCUM, int MODE>
__global__ __launch_bounds__(256) void gemm_bf16(const unsigned short* __restrict__ A,
                                                 const unsigned short* __restrict__ W,
                                                 const float* __restrict__ bias,
                                                 float* __restrict__ C,
                                                 int K, int Nreal, int ldc,
                                                 float* __restrict__ BTp,
                                                 float* __restrict__ CTp) {
    __shared__ unsigned short As[128 * 32];
    __shared__ unsigned short Ws[128 * 32];
    const int tid = threadIdx.x;
    const int lane = tid & 63;
    const int w = tid >> 6;
    const int wr = w >> 1, wc = w & 1;
    const int rowBase = blockIdx.y * 128;
    const int colBase = blockIdx.x * 128;

    const int sRow = w * 32 + (lane >> 2);
    const int sK = (lane & 3) * 8;
    const unsigned short* aSrc = A + (size_t)(rowBase + sRow) * K + sK;
    const unsigned short* wSrc = W + (size_t)(colBase + sRow) * K + sK;

    f32x4 acc[4][4];
#pragma unroll
    for (int i = 0; i < 4; ++i)
#pragma unroll
        for (int j = 0; j < 4; ++j)
            acc[i][j] = (f32x4){0.f, 0.f, 0.f, 0.f};

    for (int k0 = 0; k0 < K; k0 += 32) {
#pragma unroll
        for (int c = 0; c < 2; ++c) {
            __builtin_amdgcn_global_load_lds(
                (const __attribute__((address_space(1))) void*)(aSrc + k0 + (size_t)c * 16 * K),
                (__attribute__((address_space(3))) void*)(As + w * 1024 + c * 512), 16, 0, 0);
            __builtin_amdgcn_global_load_lds(
                (const __attribute__((address_space(1))) void*)(wSrc + k0 + (size_t)c * 16 * K),
                (__attribute__((address_space(3))) void*)(Ws + w * 1024 + c * 512), 16, 0, 0);
        }
        __syncthreads();
        short8 af[4], bfr[4];
#pragma unroll
        for (int mi = 0; mi < 4; ++mi)
            af[mi] = *(const short8*)(As + (wr * 64 + mi * 16 + (lane & 15)) * 32 + (lane >> 4) * 8);
#pragma unroll
        for (int ni = 0; ni < 4; ++ni)
            bfr[ni] = *(const short8*)(Ws + (wc * 64 + ni * 16 + (lane & 15)) * 32 + (lane >> 4) * 8);
#pragma unroll
        for (int mi = 0; mi < 4; ++mi)
#pragma unroll
            for (int ni = 0; ni < 4; ++ni)
                acc[mi][ni] = __builtin_amdgcn_mfma_f32_16x16x32_bf16(af[mi], bfr[ni], acc[mi][ni], 0, 0, 0);
        __syncthreads();
    }

#pragma unroll
    for (int mi = 0; mi < 4; ++mi) {
#pragma unroll
        for (int ni = 0; ni < 4; ++ni) {
            int col = colBase + wc * 64 + ni * 16 + (lane & 15);
            if (col < Nreal) {
#pragma unroll
                for (int r = 0; r < 4; ++r) {
                    int row = rowBase + wr * 64 + mi * 16 + (lane >> 4) * 4 + r;
                    float v = acc[mi][ni][r];
                    if (MODE == 0) {
                        if (BIAS) v += bias[col];
                        size_t idx = (size_t)row * ldc + col;
                        if (ACCUM)
                            C[idx] += v;
                        else
                            C[idx] = v;
                    } else {
                        if (col < 16)
                            C[(size_t)row * 16 + col] = v;
                        else if (col < 32)
                            BTp[(size_t)(col - 16) * 8192 + row] = v;
                        else
                            CTp[(size_t)(col - 32) * 8192 + row] = v;
                    }
                }
            }
        }
    }
}

__global__ __launch_bounds__(256) void gn2_apply_nhwc_k(float* __restrict__ f,
                                                        const float* __restrict__ stats,
                                                        const float* __restrict__ g,
                                                        const float* __restrict__ b) {
    int idx = blockIdx.x * 256 + threadIdx.x;
    if (idx >= 8 * 1024 * 256) return;
    int c = idx & 255;
    int bb = idx >> 18;
    int bg = bb * 8 + (c >> 5);
    float mean = stats[bg * 2], rstd = stats[bg * 2 + 1];
    float v = (f[idx] - mean) * rstd * g[c] + b[c];
    f[idx] = v / (1.f + __expf(-v));
}

// ---------------------------------------------------------------------------
// LayerNorm (dim 256) -> bf16 output
// ---------------------------------------------------------------------------
__global__ __launch_bounds__(256) void ln_k(const float* __restrict__ f,
                                            const float* __restrict__ g,
                                            const float* __restrict__ b,
                                            unsigned short* __restrict__ xn) {
    int row = blockIdx.x * 4 + (threadIdx.x >> 6);
    int lane = threadIdx.x & 63;
    const float* xp = f + (size_t)row * 256;
    float4 v = *(const float4*)(xp + lane * 4);
    float s = v.x + v.y + v.z + v.w;
#pragma unroll
    for (int o = 32; o > 0; o >>= 1) s += __shfl_xor(s, o);
    float mean = s * (1.f / 256.f);
    float dx = v.x - mean, dy = v.y - mean, dz = v.z - mean, dw = v.w - mean;
    float ss = dx * dx + dy * dy + dz * dz + dw * dw;
#pragma unroll
    for (int o = 32; o > 0; o >>= 1) ss += __shfl_xor(ss, o);
    float rstd = rsqrtf(ss * (1.f / 256.f) + 1e-5f);
    float4 gg = *(const float4*)(g + lane * 4);
    float4 bb = *(const float4*)(b + lane * 4);
    ushort4 o4;
    o4.x = f2bf(dx * rstd * gg.x + bb.x);
    o4.y = f2bf(dy * rstd * gg.y + bb.y);
    o4.z = f2bf(dz * rstd * gg.z + bb.z);
    o4.w = f2bf(dw * rstd * gg.w + bb.w);
    *(ushort4*)(xn + (size_t)row * 256 + lane * 4) = o4;
}

// ---------------------------------------------------------------------------
// fp32 GEMM (dt-proj, K=16, lda=16): C = softplus(A@W^T + bias)
// ---------------------------------------------------------------------------
template <int BIAS, int ACT, int ACCUM>
__global__ __launch_bounds__(256) void gemm_tn(const float* __restrict__ A,
                                               const float* __restrict__ W,
                                               const float* __restrict__ bias,
                                               float* __restrict__ C,
                                               int M, int N, int K, int lda) {
    __shared__ float As[16][68];
    __shared__ float Ws[16][68];
    const int t = threadIdx.x;
    const int tx = t & 15;
    const int ty = t >> 4;
    const int rowBase = blockIdx.y * 64;
    const int colBase = blockIdx.x * 64;
    const int lRow = t >> 2;
    const int lK = (t & 3) * 4;
    float acc[4][4] = {};
    for (int k0 = 0; k0 < K; k0 += 16) {
        {
            const float* src = A + (size_t)(rowBase + lRow) * lda + k0 + lK;
            float4 v = *(const float4*)src;
            As[lK + 0][lRow] = v.x;
            As[lK + 1][lRow] = v.y;
            As[lK + 2][lRow] = v.z;
            As[lK + 3][lRow] = v.w;
        }
        {
            int n = colBase + lRow;
            float4 v = make_float4(0.f, 0.f, 0.f, 0.f);
            if (n < N) v = *(const float4*)(W + (size_t)n * K + k0 + lK);
            Ws[lK + 0][lRow] = v.x;
            Ws[lK + 1][lRow] = v.y;
            Ws[lK + 2][lRow] = v.z;
            Ws[lK + 3][lRow] = v.w;
        }
        __syncthreads();
#pragma unroll
        for (int kk = 0; kk < 16; ++kk) {
            float4 a4 = *(const float4*)&As[kk][ty * 4];
            float4 w4 = *(const float4*)&Ws[kk][tx * 4];
            float av[4] = {a4.x, a4.y, a4.z, a4.w};
            float wv[4] = {w4.x, w4.y, w4.z, w4.w};
#pragma unroll
            for (int i = 0; i < 4; ++i)
#pragma unroll
                for (int j = 0; j < 4; ++j)
                    acc[i][j] = fmaf(av[i], wv[j], acc[i][j]);
        }
        __syncthreads();
    }
#pragma unroll
    for (int i = 0; i < 4; ++i) {
        int row = rowBase + ty * 4 + i;
#pragma unroll
        for (int j = 0; j < 4; ++j) {
            int col = colBase + tx * 4 + j;
            if (col < N) {
                float v = acc[i][j];
                if (BIAS) v += bias[col];
                if (ACT == 1) v = (v > 20.f) ? v : log1pf(__expf(v));
                size_t idx = (size_t)row * N + col;
                if (ACCUM)
                    C[idx] += v;
                else
                    C[idx] = v;
            }
        }
    }
}

// ---------------------------------------------------------------------------
// Causal depthwise conv1d (k=4) + bias + SiLU -> bf16 only
// ---------------------------------------------------------------------------
__global__ __launch_bounds__(256) void dwconv_k(const float* __restrict__ xz,
                                                const float* __restrict__ cw,
                                                const float* __restrict__ cb,
                                                unsigned short* __restrict__ xcb) {
    int idx = blockIdx.x * 256 + threadIdx.x;  // 8*1024*512
    if (idx >= 8 * 1024 * 512) return;
    int d = idx & 511;
    int tt = (idx >> 9) & 1023;
    int b = idx >> 19;
    const float* xp = xz + (size_t)b * 1024 * 1024 + d;
    float w0 = cw[d * 4], w1 = cw[d * 4 + 1], w2 = cw[d * 4 + 2], w3 = cw[d * 4 + 3];
    float acc = cb[d];
    if (tt >= 3) acc = fmaf(xp[(size_t)(tt - 3) * 1024], w0, acc);
    if (tt >= 2) acc = fmaf(xp[(size_t)(tt - 2) * 1024], w1, acc);
    if (tt >= 1) acc = fmaf(xp[(size_t)(tt - 1) * 1024], w2, acc);
    acc = fmaf(xp[(size_t)tt * 1024], w3, acc);
    float v = acc / (1.f + __expf(-acc));
    xcb[idx] = f2bf(v);
}

// ---------------------------------------------------------------------------
// Selective scan v4. Block (16 ch, batch), 256 threads (s=tid&15, dl=tid>>4).
// - dt/xv/z staged LDS transposed [ch][tt]; B/C read from transposed global
//   BT/CT[s][row] (L2-resident, sequential b128 per lane).
// - 2-deep global + 1-deep LDS software pipeline over 4-step groups.
// - DPP row_ror allreduce over the 16 s lanes; exp2 with folded log2e.
// ---------------------------------------------------------------------------
__global__ __launch_bounds__(256) void scan_k(const float* __restrict__ dtb,
                                              const float* __restrict__ BT,
                                              const float* __restrict__ CT,
                                              const unsigned short* __restrict__ xcb,
                                              const float* __restrict__ A_log,
                                              const float* __restrict__ Dp,
                                              const float* __restrict__ xz,
                                              unsigned short* __restrict__ y) {
    __shared__ float dtT[2][16][68];
    __shared__ float xvT[2][16][68];
    __shared__ float zT[2][16][68];

    const int tid = threadIdx.x;
    const int s = tid & 15;
    const int dl = tid >> 4;
    const int d0 = blockIdx.x * 16;
    const int b = blockIdx.y;

    const float A2 = -__expf(A_log[(d0 + dl) * 16 + s]) * 1.44269504f;
    const float DpV = Dp[d0 + dl];

    const int r4 = tid >> 2;
    const int c4 = (tid & 3) * 4;

    const size_t rowB = (size_t)b * 1024;
    const float* pdt = dtb + (rowB + r4) * 512 + d0 + c4;
    const unsigned short* pxv = xcb + (rowB + r4) * 512 + d0 + c4;
    const float* pz = xz + (rowB + r4) * 1024 + 512 + d0 + c4;
    const float* pB = BT + (size_t)s * 8192 + rowB;
    const float* pC = CT + (size_t)s * 8192 + rowB;

    float4 vdt = *(const float4*)pdt;
    ushort4 vxu = *(const ushort4*)pxv;
    float4 vz = *(const float4*)pz;

#define STAGE(buf)                                                                     \
    {                                                                                  \
        const float* ap = (const float*)&vdt;                                          \
        const unsigned short* xp_ = (const unsigned short*)&vxu;                       \
        const float* zp = (const float*)&vz;                                           \
        _Pragma("unroll") for (int i = 0; i < 4; ++i) {                                \
            dtT[buf][c4 + i][r4] = ap[i];                                              \
            xvT[buf][c4 + i][r4] = __uint_as_float((unsigned)xp_[i] << 16);            \
            zT[buf][c4 + i][r4] = zp[i];                                               \
        }                                                                              \
    }

    STAGE(0);
    __syncthreads();

    float h = 0.f;
    float ykeep = 0.f;
    for (int tile = 0; tile < 16; ++tile) {
        const int p = tile & 1;
        if (tile < 15) {
            size_t off = (size_t)(tile + 1) * 64;
            vdt = *(const float4*)(pdt + off * 512);
            vxu = *(const ushort4*)(pxv + off * 512);
            vz = *(const float4*)(pz + off * 1024);
        }
        const float* gB = pB + tile * 64;
        const float* gC = pC + tile * 64;
        float4 dtc = *(const float4*)&dtT[p][dl][0];
        float4 xvc = *(const float4*)&xvT[p][dl][0];
        float4 B0 = *(const float4*)(gB);
        float4 C0 = *(const float4*)(gC);
        float4 B1 = *(const float4*)(gB + 4);
        float4 C1 = *(const float4*)(gC + 4);
#pragma unroll
        for (int q4 = 0; q4 < 16; ++q4) {
            float4 dtn, xvn, Bn, Cn;
            if (q4 < 15) {
                dtn = *(const float4*)&dtT[p][dl][(q4 + 1) * 4];
                xvn = *(const float4*)&xvT[p][dl][(q4 + 1) * 4];
            }
            if (q4 < 14) {
                Bn = *(const float4*)(gB + (q4 + 2) * 4);
                Cn = *(const float4*)(gC + (q4 + 2) * 4);
            }
            const float* dtp_ = (const float*)&dtc;
            const float* xvp_ = (const float*)&xvc;
            const float* Bp_ = (const float*)&B0;
            const float* Cp_ = (const float*)&C0;
#pragma unroll
            for (int j = 0; j < 4; ++j) {
                const int tt = q4 * 4 + j;
                float dt = dtp_[j];
                float dA = exp2f(dt * A2);
                h = fmaf(dA, h, dt * xvp_[j] * Bp_[j]);
                float pr = h * Cp_[j];
                pr = dpp_add<0x121>(pr);
                pr = dpp_add<0x122>(pr);
                pr = dpp_add<0x124>(pr);
                pr = dpp_add<0x128>(pr);
                if (s == (tt & 15)) ykeep = pr;
            }
            if ((q4 & 3) == 3) {
                const int tte = (q4 >> 2) * 16 + s;
                float xve = xvT[p][dl][tte];
                float ze = zT[p][dl][tte];
                float sil = ze / (1.f + exp2f(ze * -1.44269504f));
                float yv = (ykeep + DpV * xve) * sil;
                y[(rowB + tile * 64 + tte) * 512 + d0 + dl] = f2bf(yv);
            }
            if (q4 < 15) { dtc = dtn; xvc = xvn; B0 = B1; C0 = C1; }
            if (q4 < 14) { B1 = Bn; C1 = Cn; }
        }
        if (tile < 15) STAGE(p ^ 1);
        __syncthreads();
    }
#undef STAGE
}

// ---------------------------------------------------------------------------
// Adaptive avg-pool 32x32 -> 8x8 over (B, L, C) -> bf16 feat
// ---------------------------------------------------------------------------
__global__ __launch_bounds__(256) void pool_k(const float* __restrict__ f,
                                              unsigned short* __restrict__ feat) {
    int idx = blockIdx.x * 256 + threadIdx.x;  // 8*64*256
    if (idx >= 8 * 64 * 256) return;
    int ch = idx & 255;
    int rc = (idx >> 8) & 63;
    int b = idx >> 14;
    int r = rc >> 3, c = rc & 7;
    float s = 0.f;
#pragma unroll
    for (int i = 0; i < 4; ++i)
#pragma unroll
        for (int j = 0; j < 4; ++j) {
            int l = (r * 4 + i) * 32 + (c * 4 + j);
            s += f[((size_t)b * 1024 + l) * 256 + ch];
        }
    feat[idx] = f2bf(s * (1.f / 16.f));
}

// ---------------------------------------------------------------------------
// weight conversion helpers
// ---------------------------------------------------------------------------
__global__ __launch_bounds__(256) void cvt_k(const float* __restrict__ s,
                                             unsigned short* __restrict__ d, int n4) {
    int i = blockIdx.x * 256 + threadIdx.x;
    if (i >= n4) return;
    float4 v = *(const float4*)(s + (size_t)i * 4);
    ushort4 u;
    u.x = f2bf(v.x);
    u.y = f2bf(v.y);
    u.z = f2bf(v.z);
    u.w = f2bf(v.w);
    *(ushort4*)(d + (size_t)i * 4) = u;
}

// xp_w (4,48,512) -> (4,128,512) zero-padded bf16
__global__ __launch_bounds__(256) void xpw_pad_k(const float* __restrict__ s,
                                                 unsigned short* __restrict__ d) {
    int idx = blockIdx.x * 256 + threadIdx.x;  // 4*128*512
    if (idx >= 4 * 128 * 512) return;
    int l = idx >> 16;
    int n = (idx >> 9) & 127;
    int k = idx & 511;
    d[idx] = (n < 48) ? f2bf(s[((size_t)l * 48 + n) * 512 + k]) : (unsigned short)0;
}

// conv2_w (256,128,3,3) -> w2col (256, (r*3+c)*128+ic) bf16
__global__ __launch_bounds__(256) void w2col_k(const float* __restrict__ s,
                                               unsigned short* __restrict__ d) {
    int idx = blockIdx.x * 256 + threadIdx.x;  // 256*1152
    if (idx >= 256 * 1152) return;
    int oc = idx / 1152;
    int kk = idx % 1152;
    int r3c = kk >> 7;
    int ic = kk & 127;
    d[idx] = f2bf(s[((size_t)(oc * 128 + ic)) * 9 + r3c]);
}

// ---------------------------------------------------------------------------
// launch
// ---------------------------------------------------------------------------
extern "C" void kernel_launch(void* const* d_in, const int* in_sizes, int n_in,
                              void* d_out, int out_size, void* d_ws, size_t ws_size,
                              hipStream_t stream) {
    const float* x = (const float*)d_in[0];
    const float* conv1_w = (const float*)d_in[1];
    const float* conv1_b = (const float*)d_in[2];
    const float* gn1_g = (const float*)d_in[3];
    const float* gn1_b = (const float*)d_in[4];
    const float* conv2_w = (const float*)d_in[5];
    const float* conv2_b = (const float*)d_in[6];
    const float* gn2_g = (const float*)d_in[7];
    const float* gn2_b = (const float*)d_in[8];
    const float* ln_g = (const float*)d_in[9];
    const float* ln_b = (const float*)d_in[10];
    const float* in_w = (const float*)d_in[11];
    const float* cw = (const float*)d_in[12];
    const float* cb = (const float*)d_in[13];
    const float* xp_w = (const float*)d_in[14];
    const float* dtp_w = (const float*)d_in[15];
    const float* dtp_b = (const float*)d_in[16];
    const float* A_log = (const float*)d_in[17];
    const float* Dp = (const float*)d_in[18];
    const float* out_w = (const float*)d_in[19];
    const float* head_w = (const float*)d_in[20];
    const float* head_b = (const float*)d_in[21];
    float* out = (float*)d_out;

    char* ws = (char*)d_ws;
    float* f = (float*)(ws + 0);                         //  8,388,608
    float* xz = (float*)(ws + 8388608);                  // 33,554,432 (stem: h1 fp32 / imcol bf16)
    float* xc = (float*)(ws + 41943040);                 // 16,777,216 (tail: headw_b)
    float* dtin = (float*)(ws + 58720256);               //    524,288
    float* BT = (float*)(ws + 59244544);                 //    524,288
    float* CT = (float*)(ws + 59768832);                 //    524,288
    float* dtb = (float*)(ws + 60293120);                // 16,777,216 (stem: h1nhwc bf16)
    unsigned short* xn_b = (unsigned short*)(ws + 77070336);    // 4,194,304
    unsigned short* xcb = (unsigned short*)(ws + 81264640);     // 8,388,608
    unsigned short* ybuf_b = (unsigned short*)(ws + 89653248);  // 8,388,608
    unsigned short* w2col_b = (unsigned short*)(ws + 98041856); //   589,824
    unsigned short* inw_b = (unsigned short*)(ws + 98631680);   // 2,097,152
    unsigned short* xpw_b = (unsigned short*)(ws + 100728832);  //   524,288
    unsigned short* outw_b = (unsigned short*)(ws + 101253120); // 1,048,576
    float* stats = (float*)(ws + 102301696);             // 512 B
    float* part = (float*)(ws + 102302208);              // 4 KB

    float* h1 = xz;                                      // stem alias
    unsigned short* h1n = (unsigned short*)dtb;          // stem alias
    unsigned short* imcol = (unsigned short*)xz;         // stem alias (after h1 dead)
    unsigned short* headw_b = (unsigned short*)xc;       // tail alias
    unsigned short* feat_b = (unsigned short*)dtin;      // tail alias

    // ---- weight conversions ----
    w2col_k<<<(256 * 1152 + 255) / 256, 256, 0, stream>>>(conv2_w, w2col_b);
    cvt_k<<<(1048576 / 4 + 255) / 256, 256, 0, stream>>>(in_w, inw_b, 1048576 / 4);
    xpw_pad_k<<<(4 * 128 * 512 + 255) / 256, 256, 0, stream>>>(xp_w, xpw_b);
    cvt_k<<<(524288 / 4 + 255) / 256, 256, 0, stream>>>(out_w, outw_b, 524288 / 4);

    // ---- conv stem ----
    conv1_k<<<512, 256, 0, stream>>>(x, conv1_w, conv1_b, h1);
    gn_part_k<<<512, 256, 0, stream>>>(h1, part);
    gn_reduce_k<<<1, 64, 0, stream>>>(part, stats, 1.f / 65536.f);
    gn_apply_k<<<(8 * 128 * 64 * 64 + 255) / 256, 256, 0, stream>>>(h1, stats, gn1_g, gn1_b, 128, 16, 4096, 8 * 128 * 64 * 64);
    nhwc_k<<<512, 256, 0, stream>>>(h1, h1n);
    im2col_k<<<(8192 * 9 * 8 + 255) / 256, 256, 0, stream>>>(h1n, imcol);
    gemm_bf16<1, 0, 0><<<dim3(2, 64), 256, 0, stream>>>(imcol, w2col_b, conv2_b, f, 1152, 256, 256, nullptr, nullptr);
    gn2_part_k<<<512, 256, 0, stream>>>(f, part);
    gn_reduce_k<<<1, 64, 0, stream>>>(part, stats, 1.f / 32768.f);
    gn2_apply_nhwc_k<<<(8 * 1024 * 256 + 255) / 256, 256, 0, stream>>>(f, stats, gn2_g, gn2_b);

    // ---- SSM layers ----
    for (int i = 0; i < N_LAYERS; ++i) {
        ln_k<<<2048, 256, 0, stream>>>(f, ln_g + i * 256, ln_b + i * 256, xn_b);
        gemm_bf16<0, 0, 0><<<dim3(8, 64), 256, 0, stream>>>(
            xn_b, inw_b + (size_t)i * 1024 * 256, nullptr, xz, 256, 1024, 1024, nullptr, nullptr);
        dwconv_k<<<(8 * 1024 * 512 + 255) / 256, 256, 0, stream>>>(
            xz, cw + i * 512 * 4, cb + i * 512, xcb);
        gemm_bf16<0, 0, 1><<<dim3(1, 64), 256, 0, stream>>>(
            xcb, xpw_b + (size_t)i * 128 * 512, nullptr, dtin, 512, 48, 16, BT, CT);
        gemm_tn<1, 1, 0><<<dim3(8, 128), 256, 0, stream>>>(
            dtin, dtp_w + (size_t)i * 512 * 16, dtp_b + i * 512, dtb, 8192, 512, 16, 16);
        scan_k<<<dim3(32, 8), 256, 0, stream>>>(
            dtb, BT, CT, xcb, A_log + (size_t)i * 512 * 16, Dp + i * 512, xz, ybuf_b);
        gemm_bf16<0, 1, 0><<<dim3(2, 64), 256, 0, stream>>>(
            ybuf_b, outw_b + (size_t)i * 256 * 512, nullptr, f, 512, 256, 256, nullptr, nullptr);
    }

    // ---- pool + heads ----
    cvt_k<<<(8388608 / 4 + 255) / 256, 256, 0, stream>>>(head_w, headw_b, 8388608 / 4);
    pool_k<<<(8 * 64 * 256 + 255) / 256, 256, 0, stream>>>(f, feat_b);
    for (int d = 0; d < N_DEPTHS; ++d) {
        gemm_bf16<1, 0, 0><<<dim3(64, 4), 256, 0, stream>>>(
            feat_b, headw_b + (size_t)d * N_EMB * 256, head_b + (size_t)d * N_EMB,
            out + (size_t)d * BATCH * 64 * N_EMB, 256, N_EMB, N_EMB, nullptr, nullptr);
    }
}